// Round 1
// baseline (2920.282 us; speedup 1.0000x reference)
//
#include <hip/hip_runtime.h>

#define N_NODES 50000
#define N_EDGES 800000
#define DIM     200
#define NBLK    100   // B blocks of S=2

#define TM 32         // rows per block in dense kernels

// ---------------------------------------------------------------- degree
__global__ void deg_kernel(const int* __restrict__ dst, float* __restrict__ deg) {
    int e = blockIdx.x * blockDim.x + threadIdx.x;
    if (e < N_EDGES) atomicAdd(&deg[dst[e]], 1.0f);
}

__global__ void norm_kernel(float* __restrict__ deg) {
    int n = blockIdx.x * blockDim.x + threadIdx.x;
    if (n < N_NODES) {
        float d = deg[n];
        deg[n] = d > 0.0f ? 1.0f / d : 0.0f;
    }
}

// ---------------------------------------------------------------- transpose (200x200)
__global__ void transpose_kernel(const float* __restrict__ in, float* __restrict__ out) {
    int idx = blockIdx.x * blockDim.x + threadIdx.x;
    if (idx < DIM * DIM) {
        int r = idx / DIM, c = idx % DIM;
        out[c * DIM + r] = in[idx];
    }
}

// ---------------------------------------------------------------- edge message + scatter
// one wave (64 lanes) per edge; lane handles block b (2 inputs, 2 outputs)
__global__ __launch_bounds__(256) void edge_kernel(
        const float* __restrict__ x,
        const int*   __restrict__ src,
        const int*   __restrict__ dst,
        const int*   __restrict__ et,
        const float* __restrict__ norm,
        const float* __restrict__ w,     // (R, B, 2, 2)
        float*       __restrict__ agg) {
    int wv   = (blockIdx.x * blockDim.x + threadIdx.x) >> 6;
    int lane = threadIdx.x & 63;
    if (wv >= N_EDGES) return;
    int s = src[wv], d = dst[wv], r = et[wv];
    float nrm = norm[d];
    const float* xrow = x + (size_t)s * DIM;
    const float* wrel = w + (size_t)r * (NBLK * 4);
    float* arow = agg + (size_t)d * DIM;
    #pragma unroll
    for (int pass = 0; pass < 2; ++pass) {
        int b = pass * 64 + lane;
        if (b < NBLK) {
            float x0  = xrow[2 * b];
            float x1  = xrow[2 * b + 1];
            float w00 = wrel[4 * b + 0];  // w[b][0][0]
            float w01 = wrel[4 * b + 1];  // w[b][0][1]
            float w10 = wrel[4 * b + 2];  // w[b][1][0]
            float w11 = wrel[4 * b + 3];  // w[b][1][1]
            float m0 = (x0 * w00 + x1 * w10) * nrm;
            float m1 = (x0 * w01 + x1 * w11) * nrm;
            atomicAdd(&arow[2 * b],     m0);
            atomicAdd(&arow[2 * b + 1], m1);
        }
    }
}

// ---------------------------------------------------------------- dense layer 1
// out[n,o] = tanh(agg[n,o] + sum_k x[n,k]*W[k,o] + b[o])
__global__ __launch_bounds__(256) void dense1_kernel(
        const float* __restrict__ agg,
        const float* __restrict__ x,
        const float* __restrict__ W,     // (D,D) row-major, [k*D+o]
        const float* __restrict__ b,
        float*       __restrict__ out) {
    __shared__ float s_x[TM][DIM];
    int n0 = blockIdx.x * TM;
    int tid = threadIdx.x;
    for (int idx = tid; idx < TM * DIM; idx += 256) {
        int rr = idx / DIM, cc = idx % DIM;
        int n = n0 + rr;
        s_x[rr][cc] = (n < N_NODES) ? x[(size_t)n * DIM + cc] : 0.0f;
    }
    __syncthreads();
    int c = tid & 63, rg = tid >> 6;     // cols c+64j ; rows rg*8+i
    float acc[8][4];
    #pragma unroll
    for (int i = 0; i < 8; ++i) {
        int n = n0 + rg * 8 + i;
        #pragma unroll
        for (int j = 0; j < 4; ++j) {
            int col = c + 64 * j;
            acc[i][j] = (col < DIM && n < N_NODES)
                        ? agg[(size_t)n * DIM + col] + b[col] : 0.0f;
        }
    }
    for (int k = 0; k < DIM; ++k) {
        float wv[4];
        #pragma unroll
        for (int j = 0; j < 4; ++j) {
            int col = c + 64 * j;
            wv[j] = (col < DIM) ? W[k * DIM + col] : 0.0f;
        }
        #pragma unroll
        for (int i = 0; i < 8; ++i) {
            float xv = s_x[rg * 8 + i][k];
            #pragma unroll
            for (int j = 0; j < 4; ++j) acc[i][j] += xv * wv[j];
        }
    }
    #pragma unroll
    for (int i = 0; i < 8; ++i) {
        int n = n0 + rg * 8 + i;
        if (n < N_NODES) {
            #pragma unroll
            for (int j = 0; j < 4; ++j) {
                int col = c + 64 * j;
                if (col < DIM) out[(size_t)n * DIM + col] = tanhf(acc[i][j]);
            }
        }
    }
}

// ---------------------------------------------------------------- fused layer-2 dense + RNN
// t = agg2 + h@loop_w2 + b2 ; out = tanh(t@W_ih^T + h0@W_hh^T + b_ih + b_hh)
__global__ __launch_bounds__(256) void rnn_kernel(
        const float* __restrict__ agg2,
        const float* __restrict__ h,
        const float* __restrict__ loop_w2,  // [k*D+o]
        const float* __restrict__ b2,
        const float* __restrict__ h0,
        const float* __restrict__ WihT,     // [k*D+o] = W_ih[o,k]
        const float* __restrict__ WhhT,
        const float* __restrict__ b_ih,
        const float* __restrict__ b_hh,
        float*       __restrict__ out) {
    __shared__ float s_a[TM][DIM];   // h rows, later h0 rows
    __shared__ float s_t[TM][DIM];   // t rows
    int n0 = blockIdx.x * TM;
    int tid = threadIdx.x;
    for (int idx = tid; idx < TM * DIM; idx += 256) {
        int rr = idx / DIM, cc = idx % DIM;
        int n = n0 + rr;
        s_a[rr][cc] = (n < N_NODES) ? h[(size_t)n * DIM + cc] : 0.0f;
    }
    __syncthreads();
    int c = tid & 63, rg = tid >> 6;
    float acc[8][4];
    // ---- t = agg2 + h @ loop_w2 + b2
    #pragma unroll
    for (int i = 0; i < 8; ++i) {
        int n = n0 + rg * 8 + i;
        #pragma unroll
        for (int j = 0; j < 4; ++j) {
            int col = c + 64 * j;
            acc[i][j] = (col < DIM && n < N_NODES)
                        ? agg2[(size_t)n * DIM + col] + b2[col] : 0.0f;
        }
    }
    for (int k = 0; k < DIM; ++k) {
        float wv[4];
        #pragma unroll
        for (int j = 0; j < 4; ++j) {
            int col = c + 64 * j;
            wv[j] = (col < DIM) ? loop_w2[k * DIM + col] : 0.0f;
        }
        #pragma unroll
        for (int i = 0; i < 8; ++i) {
            float xv = s_a[rg * 8 + i][k];
            #pragma unroll
            for (int j = 0; j < 4; ++j) acc[i][j] += xv * wv[j];
        }
    }
    #pragma unroll
    for (int i = 0; i < 8; ++i) {
        #pragma unroll
        for (int j = 0; j < 4; ++j) {
            int col = c + 64 * j;
            if (col < DIM) s_t[rg * 8 + i][col] = acc[i][j];
        }
    }
    __syncthreads();
    // ---- reload s_a with h0
    for (int idx = tid; idx < TM * DIM; idx += 256) {
        int rr = idx / DIM, cc = idx % DIM;
        int n = n0 + rr;
        s_a[rr][cc] = (n < N_NODES) ? h0[(size_t)n * DIM + cc] : 0.0f;
    }
    __syncthreads();
    // ---- out = tanh(t@WihT + h0@WhhT + b_ih + b_hh)
    #pragma unroll
    for (int i = 0; i < 8; ++i) {
        #pragma unroll
        for (int j = 0; j < 4; ++j) {
            int col = c + 64 * j;
            acc[i][j] = (col < DIM) ? b_ih[col] + b_hh[col] : 0.0f;
        }
    }
    for (int k = 0; k < DIM; ++k) {
        float w1v[4], w2v[4];
        #pragma unroll
        for (int j = 0; j < 4; ++j) {
            int col = c + 64 * j;
            w1v[j] = (col < DIM) ? WihT[k * DIM + col] : 0.0f;
            w2v[j] = (col < DIM) ? WhhT[k * DIM + col] : 0.0f;
        }
        #pragma unroll
        for (int i = 0; i < 8; ++i) {
            float tv = s_t[rg * 8 + i][k];
            float hv = s_a[rg * 8 + i][k];
            #pragma unroll
            for (int j = 0; j < 4; ++j) acc[i][j] += tv * w1v[j] + hv * w2v[j];
        }
    }
    #pragma unroll
    for (int i = 0; i < 8; ++i) {
        int n = n0 + rg * 8 + i;
        if (n < N_NODES) {
            #pragma unroll
            for (int j = 0; j < 4; ++j) {
                int col = c + 64 * j;
                if (col < DIM) out[(size_t)n * DIM + col] = tanhf(acc[i][j]);
            }
        }
    }
}

// ---------------------------------------------------------------- launch
extern "C" void kernel_launch(void* const* d_in, const int* in_sizes, int n_in,
                              void* d_out, int out_size, void* d_ws, size_t ws_size,
                              hipStream_t stream) {
    const float* node_feat = (const float*)d_in[0];
    const float* dyn_emb   = (const float*)d_in[1];   // (N,1,D) == (N,D)
    const int*   src       = (const int*)  d_in[2];
    const int*   dst       = (const int*)  d_in[3];
    const int*   etypes    = (const int*)  d_in[4];
    const float* w1        = (const float*)d_in[5];
    const float* loop_w1   = (const float*)d_in[6];
    const float* b1        = (const float*)d_in[7];
    const float* w2        = (const float*)d_in[8];
    const float* loop_w2   = (const float*)d_in[9];
    const float* b2        = (const float*)d_in[10];
    const float* W_ih      = (const float*)d_in[11];
    const float* W_hh      = (const float*)d_in[12];
    const float* b_ih      = (const float*)d_in[13];
    const float* b_hh      = (const float*)d_in[14];
    float* out = (float*)d_out;

    float* ws   = (float*)d_ws;
    float* norm = ws;                                  // N (padded to 65536)
    float* agg  = ws + 65536;                          // N*D
    float* h    = agg + (size_t)N_NODES * DIM;         // N*D
    float* WihT = h   + (size_t)N_NODES * DIM;         // D*D
    float* WhhT = WihT + DIM * DIM;                    // D*D

    hipMemsetAsync(norm, 0, N_NODES * sizeof(float), stream);
    hipMemsetAsync(agg,  0, (size_t)N_NODES * DIM * sizeof(float), stream);

    transpose_kernel<<<(DIM * DIM + 255) / 256, 256, 0, stream>>>(W_ih, WihT);
    transpose_kernel<<<(DIM * DIM + 255) / 256, 256, 0, stream>>>(W_hh, WhhT);

    deg_kernel <<<(N_EDGES + 255) / 256, 256, 0, stream>>>(dst, norm);
    norm_kernel<<<(N_NODES + 255) / 256, 256, 0, stream>>>(norm);

    // ---- layer 1
    edge_kernel<<<(N_EDGES + 3) / 4, 256, 0, stream>>>(
        node_feat, src, dst, etypes, norm, w1, agg);
    dense1_kernel<<<(N_NODES + TM - 1) / TM, 256, 0, stream>>>(
        agg, node_feat, loop_w1, b1, h);

    // ---- layer 2
    hipMemsetAsync(agg, 0, (size_t)N_NODES * DIM * sizeof(float), stream);
    edge_kernel<<<(N_EDGES + 3) / 4, 256, 0, stream>>>(
        h, src, dst, etypes, norm, w2, agg);

    // ---- fused layer-2 dense + RNN cell
    rnn_kernel<<<(N_NODES + TM - 1) / TM, 256, 0, stream>>>(
        agg, h, loop_w2, b2, dyn_emb, WihT, WhhT, b_ih, b_hh, out);
}

// Round 2
// 1059.568 us; speedup vs baseline: 2.7561x; 2.7561x over previous
//
#include <hip/hip_runtime.h>

#define N_NODES 50000
#define N_EDGES 800000
#define DIM     200
#define NBLK    100   // B blocks of S=2
#define NB_SCAN 196   // ceil(N_NODES/256)

#define TM 32         // rows per block in dense kernels

// ---------------------------------------------------------------- int degree
__global__ void deg_int_kernel(const int* __restrict__ dst, int* __restrict__ degi) {
    int e = blockIdx.x * blockDim.x + threadIdx.x;
    if (e < N_EDGES) atomicAdd(&degi[dst[e]], 1);
}

// ---------------------------------------------------------------- scan (exclusive) over degi -> pos
__global__ __launch_bounds__(256) void scanA(const int* __restrict__ degi,
                                             int* __restrict__ pos,
                                             int* __restrict__ bsum) {
    __shared__ int tmp[256];
    int t = threadIdx.x;
    int g = blockIdx.x * 256 + t;
    int v = (g < N_NODES) ? degi[g] : 0;
    tmp[t] = v;
    __syncthreads();
    for (int off = 1; off < 256; off <<= 1) {
        int xv = (t >= off) ? tmp[t - off] : 0;
        __syncthreads();
        tmp[t] += xv;
        __syncthreads();
    }
    if (g < N_NODES) pos[g] = tmp[t] - v;   // exclusive
    if (t == 255) bsum[blockIdx.x] = tmp[255];
}

__global__ __launch_bounds__(256) void scanB(int* __restrict__ bsum) {
    __shared__ int tmp[256];
    int t = threadIdx.x;
    int v = (t < NB_SCAN) ? bsum[t] : 0;
    tmp[t] = v;
    __syncthreads();
    for (int off = 1; off < 256; off <<= 1) {
        int xv = (t >= off) ? tmp[t - off] : 0;
        __syncthreads();
        tmp[t] += xv;
        __syncthreads();
    }
    if (t < NB_SCAN) bsum[t] = tmp[t] - v;  // exclusive block bases
}

__global__ __launch_bounds__(256) void scanC(int* __restrict__ pos, const int* __restrict__ bsum) {
    int g = blockIdx.x * 256 + threadIdx.x;
    if (g < N_NODES) pos[g] += bsum[blockIdx.x];
}

// ---------------------------------------------------------------- CSR fill (pos becomes end-pointer)
__global__ void fill_kernel(const int* __restrict__ dst, int* __restrict__ pos,
                            int* __restrict__ eidx) {
    int e = blockIdx.x * blockDim.x + threadIdx.x;
    if (e < N_EDGES) {
        int d = dst[e];
        int slot = atomicAdd(&pos[d], 1);
        eidx[slot] = e;
    }
}

// ---------------------------------------------------------------- transpose (200x200)
__global__ void transpose_kernel(const float* __restrict__ in, float* __restrict__ out) {
    int idx = blockIdx.x * blockDim.x + threadIdx.x;
    if (idx < DIM * DIM) {
        int r = idx / DIM, c = idx % DIM;
        out[c * DIM + r] = in[idx];
    }
}

// ---------------------------------------------------------------- gather aggregation
// one wave per node; lane owns block b=lane (outputs 2b,2b+1) and b=lane+64 (if <100)
__global__ __launch_bounds__(256) void gather_kernel(
        const float* __restrict__ x,
        const int*   __restrict__ src,
        const int*   __restrict__ et,
        const int*   __restrict__ endpos,  // pos after fill == end offset
        const int*   __restrict__ degi,
        const int*   __restrict__ eidx,
        const float* __restrict__ w,       // (R, B, 2, 2)
        float*       __restrict__ agg) {
    int node = (blockIdx.x * blockDim.x + threadIdx.x) >> 6;
    int lane = threadIdx.x & 63;
    if (node >= N_NODES) return;
    int deg   = degi[node];
    int end   = endpos[node];
    int start = end - deg;

    const int b0 = lane;            // < 100 always
    const int b1 = lane + 64;
    const bool has1 = (lane < NBLK - 64);

    float a00 = 0.f, a01 = 0.f, a10 = 0.f, a11 = 0.f;

    if (deg > 0) {
        int e0 = eidx[start];
        int s0 = __builtin_amdgcn_readfirstlane(src[e0]);
        int r0 = __builtin_amdgcn_readfirstlane(et[e0]);
        for (int p = start; p < end; ++p) {
            // prefetch next edge indices
            int s1 = s0, r1 = r0;
            if (p + 1 < end) {
                int e1 = eidx[p + 1];
                s1 = __builtin_amdgcn_readfirstlane(src[e1]);
                r1 = __builtin_amdgcn_readfirstlane(et[e1]);
            }
            const float* xr = x + (size_t)s0 * DIM;
            const float* wr = w + (size_t)r0 * (NBLK * 4);
            float2 xv0 = *(const float2*)(xr + 2 * b0);
            float4 wv0 = *(const float4*)(wr + 4 * b0);
            a00 += xv0.x * wv0.x + xv0.y * wv0.z;
            a01 += xv0.x * wv0.y + xv0.y * wv0.w;
            if (has1) {
                float2 xv1 = *(const float2*)(xr + 2 * b1);
                float4 wv1 = *(const float4*)(wr + 4 * b1);
                a10 += xv1.x * wv1.x + xv1.y * wv1.z;
                a11 += xv1.x * wv1.y + xv1.y * wv1.w;
            }
            s0 = s1; r0 = r1;
        }
    }
    float nrm = (deg > 0) ? 1.0f / (float)deg : 0.0f;
    float* ar = agg + (size_t)node * DIM;
    *(float2*)(ar + 2 * b0) = make_float2(a00 * nrm, a01 * nrm);
    if (has1) *(float2*)(ar + 2 * b1) = make_float2(a10 * nrm, a11 * nrm);
}

// ---------------------------------------------------------------- dense layer 1
// out[n,o] = tanh(agg[n,o] + sum_k x[n,k]*W[k,o] + b[o])
__global__ __launch_bounds__(256) void dense1_kernel(
        const float* __restrict__ agg,
        const float* __restrict__ x,
        const float* __restrict__ W,     // (D,D) row-major, [k*D+o]
        const float* __restrict__ b,
        float*       __restrict__ out) {
    __shared__ float s_x[TM][DIM];
    int n0 = blockIdx.x * TM;
    int tid = threadIdx.x;
    for (int idx = tid; idx < TM * DIM; idx += 256) {
        int rr = idx / DIM, cc = idx % DIM;
        int n = n0 + rr;
        s_x[rr][cc] = (n < N_NODES) ? x[(size_t)n * DIM + cc] : 0.0f;
    }
    __syncthreads();
    int c = tid & 63, rg = tid >> 6;     // cols c+64j ; rows rg*8+i
    float acc[8][4];
    #pragma unroll
    for (int i = 0; i < 8; ++i) {
        int n = n0 + rg * 8 + i;
        #pragma unroll
        for (int j = 0; j < 4; ++j) {
            int col = c + 64 * j;
            acc[i][j] = (col < DIM && n < N_NODES)
                        ? agg[(size_t)n * DIM + col] + b[col] : 0.0f;
        }
    }
    for (int k = 0; k < DIM; ++k) {
        float wv[4];
        #pragma unroll
        for (int j = 0; j < 4; ++j) {
            int col = c + 64 * j;
            wv[j] = (col < DIM) ? W[k * DIM + col] : 0.0f;
        }
        #pragma unroll
        for (int i = 0; i < 8; ++i) {
            float xv = s_x[rg * 8 + i][k];
            #pragma unroll
            for (int j = 0; j < 4; ++j) acc[i][j] += xv * wv[j];
        }
    }
    #pragma unroll
    for (int i = 0; i < 8; ++i) {
        int n = n0 + rg * 8 + i;
        if (n < N_NODES) {
            #pragma unroll
            for (int j = 0; j < 4; ++j) {
                int col = c + 64 * j;
                if (col < DIM) out[(size_t)n * DIM + col] = tanhf(acc[i][j]);
            }
        }
    }
}

// ---------------------------------------------------------------- fused layer-2 dense + RNN
__global__ __launch_bounds__(256) void rnn_kernel(
        const float* __restrict__ agg2,
        const float* __restrict__ h,
        const float* __restrict__ loop_w2,  // [k*D+o]
        const float* __restrict__ b2,
        const float* __restrict__ h0,
        const float* __restrict__ WihT,     // [k*D+o] = W_ih[o,k]
        const float* __restrict__ WhhT,
        const float* __restrict__ b_ih,
        const float* __restrict__ b_hh,
        float*       __restrict__ out) {
    __shared__ float s_a[TM][DIM];   // h rows, later h0 rows
    __shared__ float s_t[TM][DIM];   // t rows
    int n0 = blockIdx.x * TM;
    int tid = threadIdx.x;
    for (int idx = tid; idx < TM * DIM; idx += 256) {
        int rr = idx / DIM, cc = idx % DIM;
        int n = n0 + rr;
        s_a[rr][cc] = (n < N_NODES) ? h[(size_t)n * DIM + cc] : 0.0f;
    }
    __syncthreads();
    int c = tid & 63, rg = tid >> 6;
    float acc[8][4];
    // ---- t = agg2 + h @ loop_w2 + b2
    #pragma unroll
    for (int i = 0; i < 8; ++i) {
        int n = n0 + rg * 8 + i;
        #pragma unroll
        for (int j = 0; j < 4; ++j) {
            int col = c + 64 * j;
            acc[i][j] = (col < DIM && n < N_NODES)
                        ? agg2[(size_t)n * DIM + col] + b2[col] : 0.0f;
        }
    }
    for (int k = 0; k < DIM; ++k) {
        float wv[4];
        #pragma unroll
        for (int j = 0; j < 4; ++j) {
            int col = c + 64 * j;
            wv[j] = (col < DIM) ? loop_w2[k * DIM + col] : 0.0f;
        }
        #pragma unroll
        for (int i = 0; i < 8; ++i) {
            float xv = s_a[rg * 8 + i][k];
            #pragma unroll
            for (int j = 0; j < 4; ++j) acc[i][j] += xv * wv[j];
        }
    }
    #pragma unroll
    for (int i = 0; i < 8; ++i) {
        #pragma unroll
        for (int j = 0; j < 4; ++j) {
            int col = c + 64 * j;
            if (col < DIM) s_t[rg * 8 + i][col] = acc[i][j];
        }
    }
    __syncthreads();
    // ---- reload s_a with h0
    for (int idx = tid; idx < TM * DIM; idx += 256) {
        int rr = idx / DIM, cc = idx % DIM;
        int n = n0 + rr;
        s_a[rr][cc] = (n < N_NODES) ? h0[(size_t)n * DIM + cc] : 0.0f;
    }
    __syncthreads();
    // ---- out = tanh(t@WihT + h0@WhhT + b_ih + b_hh)
    #pragma unroll
    for (int i = 0; i < 8; ++i) {
        #pragma unroll
        for (int j = 0; j < 4; ++j) {
            int col = c + 64 * j;
            acc[i][j] = (col < DIM) ? b_ih[col] + b_hh[col] : 0.0f;
        }
    }
    for (int k = 0; k < DIM; ++k) {
        float w1v[4], w2v[4];
        #pragma unroll
        for (int j = 0; j < 4; ++j) {
            int col = c + 64 * j;
            w1v[j] = (col < DIM) ? WihT[k * DIM + col] : 0.0f;
            w2v[j] = (col < DIM) ? WhhT[k * DIM + col] : 0.0f;
        }
        #pragma unroll
        for (int i = 0; i < 8; ++i) {
            float tv = s_t[rg * 8 + i][k];
            float hv = s_a[rg * 8 + i][k];
            #pragma unroll
            for (int j = 0; j < 4; ++j) acc[i][j] += tv * w1v[j] + hv * w2v[j];
        }
    }
    #pragma unroll
    for (int i = 0; i < 8; ++i) {
        int n = n0 + rg * 8 + i;
        if (n < N_NODES) {
            #pragma unroll
            for (int j = 0; j < 4; ++j) {
                int col = c + 64 * j;
                if (col < DIM) out[(size_t)n * DIM + col] = tanhf(acc[i][j]);
            }
        }
    }
}

// ---------------------------------------------------------------- launch
extern "C" void kernel_launch(void* const* d_in, const int* in_sizes, int n_in,
                              void* d_out, int out_size, void* d_ws, size_t ws_size,
                              hipStream_t stream) {
    const float* node_feat = (const float*)d_in[0];
    const float* dyn_emb   = (const float*)d_in[1];   // (N,1,D) == (N,D)
    const int*   src       = (const int*)  d_in[2];
    const int*   dst       = (const int*)  d_in[3];
    const int*   etypes    = (const int*)  d_in[4];
    const float* w1        = (const float*)d_in[5];
    const float* loop_w1   = (const float*)d_in[6];
    const float* b1        = (const float*)d_in[7];
    const float* w2        = (const float*)d_in[8];
    const float* loop_w2   = (const float*)d_in[9];
    const float* b2        = (const float*)d_in[10];
    const float* W_ih      = (const float*)d_in[11];
    const float* W_hh      = (const float*)d_in[12];
    const float* b_ih      = (const float*)d_in[13];
    const float* b_hh      = (const float*)d_in[14];
    float* out = (float*)d_out;

    // workspace layout
    int*   degi = (int*)d_ws;                          // 51200 ints
    int*   pos  = degi + 51200;                        // 51200 ints (becomes end-ptr)
    int*   bsum = pos  + 51200;                        // 256 ints
    int*   eidx = bsum + 256;                          // 800000 ints
    float* agg  = (float*)(eidx + N_EDGES);            // N*D floats
    float* h    = agg + (size_t)N_NODES * DIM;         // N*D floats
    float* WihT = h   + (size_t)N_NODES * DIM;         // D*D
    float* WhhT = WihT + DIM * DIM;                    // D*D

    hipMemsetAsync(degi, 0, 51200 * sizeof(int), stream);

    // CSR build
    deg_int_kernel<<<(N_EDGES + 255) / 256, 256, 0, stream>>>(dst, degi);
    scanA<<<NB_SCAN, 256, 0, stream>>>(degi, pos, bsum);
    scanB<<<1, 256, 0, stream>>>(bsum);
    scanC<<<NB_SCAN, 256, 0, stream>>>(pos, bsum);
    fill_kernel<<<(N_EDGES + 255) / 256, 256, 0, stream>>>(dst, pos, eidx);

    transpose_kernel<<<(DIM * DIM + 255) / 256, 256, 0, stream>>>(W_ih, WihT);
    transpose_kernel<<<(DIM * DIM + 255) / 256, 256, 0, stream>>>(W_hh, WhhT);

    // ---- layer 1
    gather_kernel<<<(N_NODES * 64 + 255) / 256, 256, 0, stream>>>(
        node_feat, src, etypes, pos, degi, eidx, w1, agg);
    dense1_kernel<<<(N_NODES + TM - 1) / TM, 256, 0, stream>>>(
        agg, node_feat, loop_w1, b1, h);

    // ---- layer 2
    gather_kernel<<<(N_NODES * 64 + 255) / 256, 256, 0, stream>>>(
        h, src, etypes, pos, degi, eidx, w2, agg);

    // ---- fused layer-2 dense + RNN cell
    rnn_kernel<<<(N_NODES + TM - 1) / TM, 256, 0, stream>>>(
        agg, h, loop_w2, b2, dyn_emb, WihT, WhhT, b_ih, b_hh, out);
}

// Round 3
// 640.465 us; speedup vs baseline: 4.5596x; 1.6544x over previous
//
#include <hip/hip_runtime.h>

#define N_NODES 50000
#define N_EDGES 800000
#define DIM     200
#define NBLK    100   // B blocks of S=2
#define NB_SCAN 196   // ceil(N_NODES/256)
#define KPAD    224   // DIM padded to 7*32 (also 14*16)
#define NROWPAD 50048

typedef __attribute__((ext_vector_type(8)))  short short8;
typedef __attribute__((ext_vector_type(16))) float f32x16;

__device__ __forceinline__ unsigned short f2bf(float f) {
    unsigned u = __float_as_uint(f);
    u += 0x7fffu + ((u >> 16) & 1u);        // RNE (inputs finite)
    return (unsigned short)(u >> 16);
}

__device__ __forceinline__ short8 pack_bf8(float4 lo, float4 hi) {
    short8 a;
    a[0] = (short)f2bf(lo.x); a[1] = (short)f2bf(lo.y);
    a[2] = (short)f2bf(lo.z); a[3] = (short)f2bf(lo.w);
    a[4] = (short)f2bf(hi.x); a[5] = (short)f2bf(hi.y);
    a[6] = (short)f2bf(hi.z); a[7] = (short)f2bf(hi.w);
    return a;
}

// ---------------------------------------------------------------- CSR build
__global__ void deg_int_kernel(const int* __restrict__ dst, int* __restrict__ degi) {
    int e = blockIdx.x * blockDim.x + threadIdx.x;
    if (e < N_EDGES) atomicAdd(&degi[dst[e]], 1);
}

__global__ __launch_bounds__(256) void scanA(const int* __restrict__ degi,
                                             int* __restrict__ pos,
                                             int* __restrict__ bsum) {
    __shared__ int tmp[256];
    int t = threadIdx.x;
    int g = blockIdx.x * 256 + t;
    int v = (g < N_NODES) ? degi[g] : 0;
    tmp[t] = v;
    __syncthreads();
    for (int off = 1; off < 256; off <<= 1) {
        int xv = (t >= off) ? tmp[t - off] : 0;
        __syncthreads();
        tmp[t] += xv;
        __syncthreads();
    }
    if (g < N_NODES) pos[g] = tmp[t] - v;
    if (t == 255) bsum[blockIdx.x] = tmp[255];
}

__global__ __launch_bounds__(256) void scanB(int* __restrict__ bsum) {
    __shared__ int tmp[256];
    int t = threadIdx.x;
    int v = (t < NB_SCAN) ? bsum[t] : 0;
    tmp[t] = v;
    __syncthreads();
    for (int off = 1; off < 256; off <<= 1) {
        int xv = (t >= off) ? tmp[t - off] : 0;
        __syncthreads();
        tmp[t] += xv;
        __syncthreads();
    }
    if (t < NB_SCAN) bsum[t] = tmp[t] - v;
}

__global__ __launch_bounds__(256) void scanC(int* __restrict__ pos, const int* __restrict__ bsum) {
    int g = blockIdx.x * 256 + threadIdx.x;
    if (g < N_NODES) pos[g] += bsum[blockIdx.x];
}

__global__ void fill_kernel(const int* __restrict__ dst, int* __restrict__ pos,
                            int* __restrict__ eidx) {
    int e = blockIdx.x * blockDim.x + threadIdx.x;
    if (e < N_EDGES) {
        int d = dst[e];
        int slot = atomicAdd(&pos[d], 1);
        eidx[slot] = e;
    }
}

// ---------------------------------------------------------------- weight prep (bf16, padded 224x224)
// out[o][k] = w[k][o] (transpose: for x @ w layouts)
__global__ void prep_wT(const float* __restrict__ w, unsigned short* __restrict__ o) {
    int idx = blockIdx.x * blockDim.x + threadIdx.x;
    if (idx >= KPAD * KPAD) return;
    int oc = idx / KPAD, k = idx % KPAD;
    float v = (oc < DIM && k < DIM) ? w[k * DIM + oc] : 0.0f;
    o[idx] = f2bf(v);
}
// out[o][k] = w[o][k] (as-is: for x @ w^T layouts)
__global__ void prep_w(const float* __restrict__ w, unsigned short* __restrict__ o) {
    int idx = blockIdx.x * blockDim.x + threadIdx.x;
    if (idx >= KPAD * KPAD) return;
    int oc = idx / KPAD, k = idx % KPAD;
    float v = (oc < DIM && k < DIM) ? w[oc * DIM + k] : 0.0f;
    o[idx] = f2bf(v);
}

// ---------------------------------------------------------------- gather aggregation (fp32 features)
__global__ __launch_bounds__(256) void gather_f32(
        const float* __restrict__ x,
        const int*   __restrict__ src,
        const int*   __restrict__ et,
        const int*   __restrict__ endpos,
        const int*   __restrict__ degi,
        const int*   __restrict__ eidx,
        const float* __restrict__ w,
        float*       __restrict__ agg) {
    int node = (blockIdx.x * blockDim.x + threadIdx.x) >> 6;
    int lane = threadIdx.x & 63;
    if (node >= N_NODES) return;
    int deg = degi[node];
    int end = endpos[node];
    int start = end - deg;
    const int b0 = lane, b1 = lane + 64;
    const bool has1 = (lane < NBLK - 64);
    float a00 = 0.f, a01 = 0.f, a10 = 0.f, a11 = 0.f;
    if (deg > 0) {
        int e0 = eidx[start];
        int s0 = __builtin_amdgcn_readfirstlane(src[e0]);
        int r0 = __builtin_amdgcn_readfirstlane(et[e0]);
        for (int p = start; p < end; ++p) {
            int s1 = s0, r1 = r0;
            if (p + 1 < end) {
                int e1 = eidx[p + 1];
                s1 = __builtin_amdgcn_readfirstlane(src[e1]);
                r1 = __builtin_amdgcn_readfirstlane(et[e1]);
            }
            const float* xr = x + (size_t)s0 * DIM;
            const float* wr = w + (size_t)r0 * (NBLK * 4);
            float2 xv0 = *(const float2*)(xr + 2 * b0);
            float4 wv0 = *(const float4*)(wr + 4 * b0);
            a00 += xv0.x * wv0.x + xv0.y * wv0.z;
            a01 += xv0.x * wv0.y + xv0.y * wv0.w;
            if (has1) {
                float2 xv1 = *(const float2*)(xr + 2 * b1);
                float4 wv1 = *(const float4*)(wr + 4 * b1);
                a10 += xv1.x * wv1.x + xv1.y * wv1.z;
                a11 += xv1.x * wv1.y + xv1.y * wv1.w;
            }
            s0 = s1; r0 = r1;
        }
    }
    float nrm = (deg > 0) ? 1.0f / (float)deg : 0.0f;
    float* ar = agg + (size_t)node * DIM;
    *(float2*)(ar + 2 * b0) = make_float2(a00 * nrm, a01 * nrm);
    if (has1) *(float2*)(ar + 2 * b1) = make_float2(a10 * nrm, a11 * nrm);
}

// ---------------------------------------------------------------- gather aggregation (bf16 features, stride KPAD)
__global__ __launch_bounds__(256) void gather_bf16(
        const unsigned short* __restrict__ x,
        const int*   __restrict__ src,
        const int*   __restrict__ et,
        const int*   __restrict__ endpos,
        const int*   __restrict__ degi,
        const int*   __restrict__ eidx,
        const float* __restrict__ w,
        float*       __restrict__ agg) {
    int node = (blockIdx.x * blockDim.x + threadIdx.x) >> 6;
    int lane = threadIdx.x & 63;
    if (node >= N_NODES) return;
    int deg = degi[node];
    int end = endpos[node];
    int start = end - deg;
    const int b0 = lane, b1 = lane + 64;
    const bool has1 = (lane < NBLK - 64);
    float a00 = 0.f, a01 = 0.f, a10 = 0.f, a11 = 0.f;
    if (deg > 0) {
        int e0 = eidx[start];
        int s0 = __builtin_amdgcn_readfirstlane(src[e0]);
        int r0 = __builtin_amdgcn_readfirstlane(et[e0]);
        for (int p = start; p < end; ++p) {
            int s1 = s0, r1 = r0;
            if (p + 1 < end) {
                int e1 = eidx[p + 1];
                s1 = __builtin_amdgcn_readfirstlane(src[e1]);
                r1 = __builtin_amdgcn_readfirstlane(et[e1]);
            }
            const unsigned short* xr = x + (size_t)s0 * KPAD;
            const float* wr = w + (size_t)r0 * (NBLK * 4);
            unsigned u0 = *(const unsigned*)(xr + 2 * b0);
            float x0 = __uint_as_float(u0 << 16);
            float x1 = __uint_as_float(u0 & 0xffff0000u);
            float4 wv0 = *(const float4*)(wr + 4 * b0);
            a00 += x0 * wv0.x + x1 * wv0.z;
            a01 += x0 * wv0.y + x1 * wv0.w;
            if (has1) {
                unsigned u1 = *(const unsigned*)(xr + 2 * b1);
                float x2 = __uint_as_float(u1 << 16);
                float x3 = __uint_as_float(u1 & 0xffff0000u);
                float4 wv1 = *(const float4*)(wr + 4 * b1);
                a10 += x2 * wv1.x + x3 * wv1.z;
                a11 += x2 * wv1.y + x3 * wv1.w;
            }
            s0 = s1; r0 = r1;
        }
    }
    float nrm = (deg > 0) ? 1.0f / (float)deg : 0.0f;
    float* ar = agg + (size_t)node * DIM;
    *(float2*)(ar + 2 * b0) = make_float2(a00 * nrm, a01 * nrm);
    if (has1) *(float2*)(ar + 2 * b1) = make_float2(a10 * nrm, a11 * nrm);
}

// ---------------------------------------------------------------- GEMM1: hb = bf16(tanh(agg1 + x@loop_w1 + b1))
// one wave per 32 rows; wave computes 32x224 with 7 n-tiles of 32x32x16 MFMA
__global__ __launch_bounds__(64) void gemm1_kernel(
        const float* __restrict__ x,          // [50000][200]
        const float* __restrict__ agg1,       // [50000][200]
        const float* __restrict__ b1,         // [200]
        const unsigned short* __restrict__ w1T, // [224][224] = loop_w1^T bf16
        unsigned short* __restrict__ hb) {    // [50048][224]
    int row0 = blockIdx.x * 32;
    int l = threadIdx.x;
    int rl = l & 31, hl = l >> 5;
    int arow = row0 + rl;
    const bool arv = (arow < N_NODES);
    f32x16 acc[7] = {};
    for (int ks = 0; ks < 13; ++ks) {
        int k0 = ks * 16 + hl * 8;
        short8 af = {0, 0, 0, 0, 0, 0, 0, 0};
        if (arv && k0 < DIM) {
            const float* ap = x + (size_t)arow * DIM + k0;
            af = pack_bf8(*(const float4*)ap, *(const float4*)(ap + 4));
        }
        const unsigned short* wp = w1T + (size_t)rl * KPAD + k0;
        #pragma unroll
        for (int nt = 0; nt < 7; ++nt) {
            short8 bf = *(const short8*)(wp + nt * 32 * KPAD);
            acc[nt] = __builtin_amdgcn_mfma_f32_32x32x16_bf16(af, bf, acc[nt], 0, 0, 0);
        }
    }
    #pragma unroll
    for (int nt = 0; nt < 7; ++nt) {
        int gc = nt * 32 + rl;
        float bias = (gc < DIM) ? b1[gc] : 0.0f;
        #pragma unroll
        for (int r = 0; r < 16; ++r) {
            int gr = row0 + (r & 3) + 8 * (r >> 2) + 4 * hl;
            float v = 0.0f;
            if (gc < DIM && gr < N_NODES)
                v = acc[nt][r] + agg1[(size_t)gr * DIM + gc] + bias;
            hb[(size_t)gr * KPAD + gc] = f2bf(tanhf(v));
        }
    }
}

// ---------------------------------------------------------------- GEMM2 (fused RNN):
// t = agg2 + hb@loop_w2 + b2 ; out = tanh(t@W_ih^T + h0@W_hh^T + b_ih + b_hh)
__global__ __launch_bounds__(64) void gemm2_kernel(
        const unsigned short* __restrict__ hb,   // [50048][224]
        const float* __restrict__ agg2,          // [50000][200]
        const float* __restrict__ b2,
        const unsigned short* __restrict__ w2T,  // [224][224]
        const float* __restrict__ h0,            // [50000][200]
        const unsigned short* __restrict__ wihb, // [224][224] = W_ih bf16
        const unsigned short* __restrict__ whhb, // [224][224] = W_hh bf16
        const float* __restrict__ b_ih,
        const float* __restrict__ b_hh,
        float* __restrict__ out) {
    __shared__ unsigned short t_lds[32 * KPAD];  // 14 KB, XOR-swizzled
    int row0 = blockIdx.x * 32;
    int l = threadIdx.x;
    int rl = l & 31, hl = l >> 5;

    // ---- phase A: t = agg2 + hb @ loop_w2 + b2
    {
        f32x16 acc[7] = {};
        for (int ks = 0; ks < 13; ++ks) {
            int k0 = ks * 16 + hl * 8;
            short8 af = *(const short8*)(hb + (size_t)(row0 + rl) * KPAD + k0);
            const unsigned short* wp = w2T + (size_t)rl * KPAD + k0;
            #pragma unroll
            for (int nt = 0; nt < 7; ++nt) {
                short8 bf = *(const short8*)(wp + nt * 32 * KPAD);
                acc[nt] = __builtin_amdgcn_mfma_f32_32x32x16_bf16(af, bf, acc[nt], 0, 0, 0);
            }
        }
        #pragma unroll
        for (int nt = 0; nt < 7; ++nt) {
            int gc = nt * 32 + rl;
            float bias = (gc < DIM) ? b2[gc] : 0.0f;
            #pragma unroll
            for (int r = 0; r < 16; ++r) {
                int lr = (r & 3) + 8 * (r >> 2) + 4 * hl;
                int gr = row0 + lr;
                float v = 0.0f;
                if (gc < DIM) {
                    v = acc[nt][r] + bias;
                    if (gr < N_NODES) v += agg2[(size_t)gr * DIM + gc];
                }
                unsigned wb = (unsigned)(lr * (KPAD * 2) + gc * 2) ^ (unsigned)((lr & 15) << 4);
                *(unsigned short*)((char*)t_lds + wb) = f2bf(v);
            }
        }
    }
    __syncthreads();

    // ---- phase B: out = tanh(t@W_ih^T + h0@W_hh^T + b_ih + b_hh)
    f32x16 o[7] = {};
    int arow = row0 + rl;
    const bool arv = (arow < N_NODES);
    for (int ks = 0; ks < 13; ++ks) {
        int k0 = ks * 16 + hl * 8;
        unsigned tb = (unsigned)(rl * (KPAD * 2) + k0 * 2) ^ (unsigned)((rl & 15) << 4);
        short8 tf = *(const short8*)((const char*)t_lds + tb);
        short8 hf = {0, 0, 0, 0, 0, 0, 0, 0};
        if (arv && k0 < DIM) {
            const float* hp = h0 + (size_t)arow * DIM + k0;
            hf = pack_bf8(*(const float4*)hp, *(const float4*)(hp + 4));
        }
        const unsigned short* wp1 = wihb + (size_t)rl * KPAD + k0;
        const unsigned short* wp2 = whhb + (size_t)rl * KPAD + k0;
        #pragma unroll
        for (int nt = 0; nt < 7; ++nt) {
            short8 bf1 = *(const short8*)(wp1 + nt * 32 * KPAD);
            o[nt] = __builtin_amdgcn_mfma_f32_32x32x16_bf16(tf, bf1, o[nt], 0, 0, 0);
            short8 bf2 = *(const short8*)(wp2 + nt * 32 * KPAD);
            o[nt] = __builtin_amdgcn_mfma_f32_32x32x16_bf16(hf, bf2, o[nt], 0, 0, 0);
        }
    }
    #pragma unroll
    for (int nt = 0; nt < 7; ++nt) {
        int gc = nt * 32 + rl;
        if (gc >= DIM) continue;
        float bias = b_ih[gc] + b_hh[gc];
        #pragma unroll
        for (int r = 0; r < 16; ++r) {
            int gr = row0 + (r & 3) + 8 * (r >> 2) + 4 * hl;
            if (gr < N_NODES)
                out[(size_t)gr * DIM + gc] = tanhf(o[nt][r] + bias);
        }
    }
}

// ---------------------------------------------------------------- launch
extern "C" void kernel_launch(void* const* d_in, const int* in_sizes, int n_in,
                              void* d_out, int out_size, void* d_ws, size_t ws_size,
                              hipStream_t stream) {
    const float* node_feat = (const float*)d_in[0];
    const float* dyn_emb   = (const float*)d_in[1];
    const int*   src       = (const int*)  d_in[2];
    const int*   dst       = (const int*)  d_in[3];
    const int*   etypes    = (const int*)  d_in[4];
    const float* w1        = (const float*)d_in[5];
    const float* loop_w1   = (const float*)d_in[6];
    const float* b1        = (const float*)d_in[7];
    const float* w2        = (const float*)d_in[8];
    const float* loop_w2   = (const float*)d_in[9];
    const float* b2        = (const float*)d_in[10];
    const float* W_ih      = (const float*)d_in[11];
    const float* W_hh      = (const float*)d_in[12];
    const float* b_ih      = (const float*)d_in[13];
    const float* b_hh      = (const float*)d_in[14];
    float* out = (float*)d_out;

    // workspace layout
    int*   degi = (int*)d_ws;                          // 51200
    int*   pos  = degi + 51200;                        // 51200
    int*   bsum = pos  + 51200;                        // 256
    int*   eidx = bsum + 256;                          // 800000
    float* agg  = (float*)(eidx + N_EDGES);            // N*D fp32 (40 MB)
    unsigned short* hb  = (unsigned short*)(agg + (size_t)N_NODES * DIM);  // 50048*224
    unsigned short* w1T = hb  + (size_t)NROWPAD * KPAD;
    unsigned short* w2T = w1T + KPAD * KPAD;
    unsigned short* wihb = w2T + KPAD * KPAD;
    unsigned short* whhb = wihb + KPAD * KPAD;

    hipMemsetAsync(degi, 0, 51200 * sizeof(int), stream);

    // CSR build
    deg_int_kernel<<<(N_EDGES + 255) / 256, 256, 0, stream>>>(dst, degi);
    scanA<<<NB_SCAN, 256, 0, stream>>>(degi, pos, bsum);
    scanB<<<1, 256, 0, stream>>>(bsum);
    scanC<<<NB_SCAN, 256, 0, stream>>>(pos, bsum);
    fill_kernel<<<(N_EDGES + 255) / 256, 256, 0, stream>>>(dst, pos, eidx);

    // weight prep (bf16)
    prep_wT<<<(KPAD * KPAD + 255) / 256, 256, 0, stream>>>(loop_w1, w1T);
    prep_wT<<<(KPAD * KPAD + 255) / 256, 256, 0, stream>>>(loop_w2, w2T);
    prep_w <<<(KPAD * KPAD + 255) / 256, 256, 0, stream>>>(W_ih, wihb);
    prep_w <<<(KPAD * KPAD + 255) / 256, 256, 0, stream>>>(W_hh, whhb);

    // ---- layer 1
    gather_f32<<<(N_NODES * 64 + 255) / 256, 256, 0, stream>>>(
        node_feat, src, etypes, pos, degi, eidx, w1, agg);
    gemm1_kernel<<<(N_NODES + 31) / 32, 64, 0, stream>>>(
        node_feat, agg, b1, w1T, hb);

    // ---- layer 2
    gather_bf16<<<(N_NODES * 64 + 255) / 256, 256, 0, stream>>>(
        hb, src, etypes, pos, degi, eidx, w2, agg);

    // ---- fused layer-2 dense + RNN cell
    gemm2_kernel<<<(N_NODES + 31) / 32, 64, 0, stream>>>(
        hb, agg, b2, w2T, dyn_emb, wihb, whhb, b_ih, b_hh, out);
}

// Round 4
// 524.201 us; speedup vs baseline: 5.5709x; 1.2218x over previous
//
#include <hip/hip_runtime.h>

#define N_NODES 50000
#define N_EDGES 800000
#define DIM     200
#define NBLK    100   // B blocks of S=2
#define NB_SCAN 196   // ceil(N_NODES/256)
#define KPAD    224   // DIM padded to 7*32
#define NROWPAD 50048

typedef __attribute__((ext_vector_type(8)))  short short8;
typedef __attribute__((ext_vector_type(16))) float f32x16;

__device__ __forceinline__ unsigned short f2bf(float f) {
    unsigned u = __float_as_uint(f);
    u += 0x7fffu + ((u >> 16) & 1u);        // RNE (inputs finite)
    return (unsigned short)(u >> 16);
}

__device__ __forceinline__ short8 pack_bf8(float4 lo, float4 hi) {
    short8 a;
    a[0] = (short)f2bf(lo.x); a[1] = (short)f2bf(lo.y);
    a[2] = (short)f2bf(lo.z); a[3] = (short)f2bf(lo.w);
    a[4] = (short)f2bf(hi.x); a[5] = (short)f2bf(hi.y);
    a[6] = (short)f2bf(hi.z); a[7] = (short)f2bf(hi.w);
    return a;
}

__device__ __forceinline__ int uread(int v, int l) {
    return __builtin_amdgcn_readlane(v, l);
}

// ---------------------------------------------------------------- CSR build
__global__ void deg_int_kernel(const int* __restrict__ dst, int* __restrict__ degi) {
    int e = blockIdx.x * blockDim.x + threadIdx.x;
    if (e < N_EDGES) atomicAdd(&degi[dst[e]], 1);
}

__global__ __launch_bounds__(256) void scanA(const int* __restrict__ degi,
                                             int* __restrict__ pos,
                                             int* __restrict__ bsum) {
    __shared__ int tmp[256];
    int t = threadIdx.x;
    int g = blockIdx.x * 256 + t;
    int v = (g < N_NODES) ? degi[g] : 0;
    tmp[t] = v;
    __syncthreads();
    for (int off = 1; off < 256; off <<= 1) {
        int xv = (t >= off) ? tmp[t - off] : 0;
        __syncthreads();
        tmp[t] += xv;
        __syncthreads();
    }
    if (g < N_NODES) pos[g] = tmp[t] - v;
    if (t == 255) bsum[blockIdx.x] = tmp[255];
}

__global__ __launch_bounds__(256) void scanB(int* __restrict__ bsum) {
    __shared__ int tmp[256];
    int t = threadIdx.x;
    int v = (t < NB_SCAN) ? bsum[t] : 0;
    tmp[t] = v;
    __syncthreads();
    for (int off = 1; off < 256; off <<= 1) {
        int xv = (t >= off) ? tmp[t - off] : 0;
        __syncthreads();
        tmp[t] += xv;
        __syncthreads();
    }
    if (t < NB_SCAN) bsum[t] = tmp[t] - v;
}

__global__ __launch_bounds__(256) void scanC(int* __restrict__ pos, const int* __restrict__ bsum) {
    int g = blockIdx.x * 256 + threadIdx.x;
    if (g < N_NODES) pos[g] += bsum[blockIdx.x];
}

// fill: pos becomes end-pointer; se[slot] = (src, etype) sorted by dst
__global__ void fill_kernel(const int* __restrict__ src, const int* __restrict__ dst,
                            const int* __restrict__ et,
                            int* __restrict__ pos, int2* __restrict__ se) {
    int e = blockIdx.x * blockDim.x + threadIdx.x;
    if (e < N_EDGES) {
        int d = dst[e];
        int slot = atomicAdd(&pos[d], 1);
        se[slot] = make_int2(src[e], et[e]);
    }
}

// ---------------------------------------------------------------- weight prep (bf16, padded 224x224)
__global__ void prep_wT(const float* __restrict__ w, unsigned short* __restrict__ o) {
    int idx = blockIdx.x * blockDim.x + threadIdx.x;
    if (idx >= KPAD * KPAD) return;
    int oc = idx / KPAD, k = idx % KPAD;
    float v = (oc < DIM && k < DIM) ? w[k * DIM + oc] : 0.0f;
    o[idx] = f2bf(v);
}
__global__ void prep_w(const float* __restrict__ w, unsigned short* __restrict__ o) {
    int idx = blockIdx.x * blockDim.x + threadIdx.x;
    if (idx >= KPAD * KPAD) return;
    int oc = idx / KPAD, k = idx % KPAD;
    float v = (oc < DIM && k < DIM) ? w[oc * DIM + k] : 0.0f;
    o[idx] = f2bf(v);
}

// ---------------------------------------------------------------- pipelined gather (fp32 features)
#define GLOAD_F32(QQ, X0, X1, W0, W1)                                   \
    { int s_ = uread(sv, (QQ)); int r_ = uread(rv, (QQ));               \
      const float* xr_ = x + (size_t)s_ * DIM;                          \
      const float* wr_ = w + (size_t)r_ * (NBLK * 4);                   \
      X0 = *(const float2*)(xr_ + 2 * b0);                              \
      W0 = *(const float4*)(wr_ + 4 * b0);                              \
      if (has1) { X1 = *(const float2*)(xr_ + 2 * b1);                  \
                  W1 = *(const float4*)(wr_ + 4 * b1); } }

__global__ __launch_bounds__(256) void gatherP_f32(
        const float* __restrict__ x,
        const int2*  __restrict__ se,
        const int*   __restrict__ endpos,
        const int*   __restrict__ degi,
        const float* __restrict__ w,
        float*       __restrict__ agg) {
    int node = (blockIdx.x * blockDim.x + threadIdx.x) >> 6;
    int lane = threadIdx.x & 63;
    if (node >= N_NODES) return;
    int deg   = __builtin_amdgcn_readfirstlane(degi[node]);
    int end   = __builtin_amdgcn_readfirstlane(endpos[node]);
    int start = end - deg;
    const int b0 = lane, b1 = lane + 64;
    const bool has1 = (lane < NBLK - 64);
    float a00 = 0.f, a01 = 0.f, a10 = 0.f, a11 = 0.f;
    float c00 = 0.f, c01 = 0.f, c10 = 0.f, c11 = 0.f;

    for (int base = start; base < end; base += 64) {
        int cnt = end - base; if (cnt > 64) cnt = 64;
        int2 sei = se[base + (lane < cnt ? lane : cnt - 1)];
        int sv = sei.x, rv = sei.y;

        float2 xA0 = {0,0}, xA1 = {0,0}, xB0 = {0,0}, xB1 = {0,0};
        float4 wA0 = {0,0,0,0}, wA1 = {0,0,0,0}, wB0 = {0,0,0,0}, wB1 = {0,0,0,0};
        float2 xN0, xN1, xM0, xM1;
        float4 wN0, wN1, wM0, wM1;

        GLOAD_F32(0, xA0, xA1, wA0, wA1);
        if (cnt > 1) GLOAD_F32(1, xB0, xB1, wB0, wB1);

        for (int q = 0; q < cnt; q += 2) {
            if (q + 2 < cnt) {
                GLOAD_F32(q + 2, xN0, xN1, wN0, wN1);
                if (q + 3 < cnt) GLOAD_F32(q + 3, xM0, xM1, wM0, wM1);
            }
            a00 += xA0.x * wA0.x + xA0.y * wA0.z;
            a01 += xA0.x * wA0.y + xA0.y * wA0.w;
            if (has1) {
                a10 += xA1.x * wA1.x + xA1.y * wA1.z;
                a11 += xA1.x * wA1.y + xA1.y * wA1.w;
            }
            if (q + 1 < cnt) {
                c00 += xB0.x * wB0.x + xB0.y * wB0.z;
                c01 += xB0.x * wB0.y + xB0.y * wB0.w;
                if (has1) {
                    c10 += xB1.x * wB1.x + xB1.y * wB1.z;
                    c11 += xB1.x * wB1.y + xB1.y * wB1.w;
                }
            }
            xA0 = xN0; xA1 = xN1; wA0 = wN0; wA1 = wN1;
            xB0 = xM0; xB1 = xM1; wB0 = wM0; wB1 = wM1;
        }
    }
    float nrm = (deg > 0) ? 1.0f / (float)deg : 0.0f;
    float* ar = agg + (size_t)node * DIM;
    *(float2*)(ar + 2 * b0) = make_float2((a00 + c00) * nrm, (a01 + c01) * nrm);
    if (has1) *(float2*)(ar + 2 * b1) = make_float2((a10 + c10) * nrm, (a11 + c11) * nrm);
}

// ---------------------------------------------------------------- pipelined gather (bf16 features, stride KPAD)
#define GLOAD_BF16(QQ, U0, U1, W0, W1)                                  \
    { int s_ = uread(sv, (QQ)); int r_ = uread(rv, (QQ));               \
      const unsigned short* xr_ = x + (size_t)s_ * KPAD;                \
      const float* wr_ = w + (size_t)r_ * (NBLK * 4);                   \
      U0 = *(const unsigned*)(xr_ + 2 * b0);                            \
      W0 = *(const float4*)(wr_ + 4 * b0);                              \
      if (has1) { U1 = *(const unsigned*)(xr_ + 2 * b1);                \
                  W1 = *(const float4*)(wr_ + 4 * b1); } }

__global__ __launch_bounds__(256) void gatherP_bf16(
        const unsigned short* __restrict__ x,
        const int2*  __restrict__ se,
        const int*   __restrict__ endpos,
        const int*   __restrict__ degi,
        const float* __restrict__ w,
        float*       __restrict__ agg) {
    int node = (blockIdx.x * blockDim.x + threadIdx.x) >> 6;
    int lane = threadIdx.x & 63;
    if (node >= N_NODES) return;
    int deg   = __builtin_amdgcn_readfirstlane(degi[node]);
    int end   = __builtin_amdgcn_readfirstlane(endpos[node]);
    int start = end - deg;
    const int b0 = lane, b1 = lane + 64;
    const bool has1 = (lane < NBLK - 64);
    float a00 = 0.f, a01 = 0.f, a10 = 0.f, a11 = 0.f;
    float c00 = 0.f, c01 = 0.f, c10 = 0.f, c11 = 0.f;

    for (int base = start; base < end; base += 64) {
        int cnt = end - base; if (cnt > 64) cnt = 64;
        int2 sei = se[base + (lane < cnt ? lane : cnt - 1)];
        int sv = sei.x, rv = sei.y;

        unsigned uA0 = 0, uA1 = 0, uB0 = 0, uB1 = 0;
        float4 wA0 = {0,0,0,0}, wA1 = {0,0,0,0}, wB0 = {0,0,0,0}, wB1 = {0,0,0,0};
        unsigned uN0, uN1, uM0, uM1;
        float4 wN0, wN1, wM0, wM1;

        GLOAD_BF16(0, uA0, uA1, wA0, wA1);
        if (cnt > 1) GLOAD_BF16(1, uB0, uB1, wB0, wB1);

        for (int q = 0; q < cnt; q += 2) {
            if (q + 2 < cnt) {
                GLOAD_BF16(q + 2, uN0, uN1, wN0, wN1);
                if (q + 3 < cnt) GLOAD_BF16(q + 3, uM0, uM1, wM0, wM1);
            }
            {
                float x0 = __uint_as_float(uA0 << 16);
                float x1 = __uint_as_float(uA0 & 0xffff0000u);
                a00 += x0 * wA0.x + x1 * wA0.z;
                a01 += x0 * wA0.y + x1 * wA0.w;
                if (has1) {
                    float x2 = __uint_as_float(uA1 << 16);
                    float x3 = __uint_as_float(uA1 & 0xffff0000u);
                    a10 += x2 * wA1.x + x3 * wA1.z;
                    a11 += x2 * wA1.y + x3 * wA1.w;
                }
            }
            if (q + 1 < cnt) {
                float x0 = __uint_as_float(uB0 << 16);
                float x1 = __uint_as_float(uB0 & 0xffff0000u);
                c00 += x0 * wB0.x + x1 * wB0.z;
                c01 += x0 * wB0.y + x1 * wB0.w;
                if (has1) {
                    float x2 = __uint_as_float(uB1 << 16);
                    float x3 = __uint_as_float(uB1 & 0xffff0000u);
                    c10 += x2 * wB1.x + x3 * wB1.z;
                    c11 += x2 * wB1.y + x3 * wB1.w;
                }
            }
            uA0 = uN0; uA1 = uN1; wA0 = wN0; wA1 = wN1;
            uB0 = uM0; uB1 = uM1; wB0 = wM0; wB1 = wM1;
        }
    }
    float nrm = (deg > 0) ? 1.0f / (float)deg : 0.0f;
    float* ar = agg + (size_t)node * DIM;
    *(float2*)(ar + 2 * b0) = make_float2((a00 + c00) * nrm, (a01 + c01) * nrm);
    if (has1) *(float2*)(ar + 2 * b1) = make_float2((a10 + c10) * nrm, (a11 + c11) * nrm);
}

// ---------------------------------------------------------------- GEMM1: hb = bf16(tanh(agg1 + x@loop_w1 + b1))
// 128 threads = 2 waves per 32-row tile; wave0 -> nt 0..3, wave1 -> nt 4..6
__global__ __launch_bounds__(128) void gemm1_kernel(
        const float* __restrict__ x,
        const float* __restrict__ agg1,
        const float* __restrict__ b1,
        const unsigned short* __restrict__ w1T,
        unsigned short* __restrict__ hb) {
    int row0 = blockIdx.x * 32;
    int tid = threadIdx.x;
    int l = tid & 63;
    int wvid = tid >> 6;
    int rl = l & 31, hl = l >> 5;
    int ntlo = wvid * 4;
    int arow = row0 + rl;
    const bool arv = (arow < N_NODES);
    f32x16 acc[4] = {};
    for (int ks = 0; ks < 13; ++ks) {
        int k0 = ks * 16 + hl * 8;
        short8 af = {0, 0, 0, 0, 0, 0, 0, 0};
        if (arv && k0 < DIM) {
            const float* ap = x + (size_t)arow * DIM + k0;
            af = pack_bf8(*(const float4*)ap, *(const float4*)(ap + 4));
        }
        const unsigned short* wp = w1T + (size_t)(ntlo * 32 + rl) * KPAD + k0;
        #pragma unroll
        for (int t = 0; t < 4; ++t) {
            if (ntlo + t < 7) {
                short8 bf = *(const short8*)(wp + t * 32 * KPAD);
                acc[t] = __builtin_amdgcn_mfma_f32_32x32x16_bf16(af, bf, acc[t], 0, 0, 0);
            }
        }
    }
    #pragma unroll
    for (int t = 0; t < 4; ++t) {
        if (ntlo + t >= 7) continue;
        int gc = (ntlo + t) * 32 + rl;
        float bias = (gc < DIM) ? b1[gc] : 0.0f;
        #pragma unroll
        for (int r = 0; r < 16; ++r) {
            int gr = row0 + (r & 3) + 8 * (r >> 2) + 4 * hl;
            float v = 0.0f;
            if (gc < DIM && gr < N_NODES)
                v = acc[t][r] + agg1[(size_t)gr * DIM + gc] + bias;
            hb[(size_t)gr * KPAD + gc] = f2bf(tanhf(v));
        }
    }
}

// ---------------------------------------------------------------- GEMM2 (fused RNN), 2 waves/tile
__global__ __launch_bounds__(128) void gemm2_kernel(
        const unsigned short* __restrict__ hb,
        const float* __restrict__ agg2,
        const float* __restrict__ b2,
        const unsigned short* __restrict__ w2T,
        const float* __restrict__ h0,
        const unsigned short* __restrict__ wihb,
        const unsigned short* __restrict__ whhb,
        const float* __restrict__ b_ih,
        const float* __restrict__ b_hh,
        float* __restrict__ out) {
    __shared__ unsigned short t_lds[32 * KPAD];  // 14 KB, XOR-swizzled
    int row0 = blockIdx.x * 32;
    int tid = threadIdx.x;
    int l = tid & 63;
    int wvid = tid >> 6;
    int rl = l & 31, hl = l >> 5;
    int ntlo = wvid * 4;

    // ---- phase A: t = agg2 + hb @ loop_w2 + b2
    {
        f32x16 acc[4] = {};
        for (int ks = 0; ks < 13; ++ks) {
            int k0 = ks * 16 + hl * 8;
            short8 af = *(const short8*)(hb + (size_t)(row0 + rl) * KPAD + k0);
            const unsigned short* wp = w2T + (size_t)(ntlo * 32 + rl) * KPAD + k0;
            #pragma unroll
            for (int t = 0; t < 4; ++t) {
                if (ntlo + t < 7) {
                    short8 bf = *(const short8*)(wp + t * 32 * KPAD);
                    acc[t] = __builtin_amdgcn_mfma_f32_32x32x16_bf16(af, bf, acc[t], 0, 0, 0);
                }
            }
        }
        #pragma unroll
        for (int t = 0; t < 4; ++t) {
            if (ntlo + t >= 7) continue;
            int gc = (ntlo + t) * 32 + rl;
            float bias = (gc < DIM) ? b2[gc] : 0.0f;
            #pragma unroll
            for (int r = 0; r < 16; ++r) {
                int lr = (r & 3) + 8 * (r >> 2) + 4 * hl;
                int gr = row0 + lr;
                float v = 0.0f;
                if (gc < DIM) {
                    v = acc[t][r] + bias;
                    if (gr < N_NODES) v += agg2[(size_t)gr * DIM + gc];
                }
                unsigned wb = (unsigned)(lr * (KPAD * 2) + gc * 2) ^ (unsigned)((lr & 15) << 4);
                *(unsigned short*)((char*)t_lds + wb) = f2bf(v);
            }
        }
    }
    __syncthreads();

    // ---- phase B: out = tanh(t@W_ih^T + h0@W_hh^T + b_ih + b_hh)
    f32x16 o[4] = {};
    int arow = row0 + rl;
    const bool arv = (arow < N_NODES);
    for (int ks = 0; ks < 13; ++ks) {
        int k0 = ks * 16 + hl * 8;
        unsigned tb = (unsigned)(rl * (KPAD * 2) + k0 * 2) ^ (unsigned)((rl & 15) << 4);
        short8 tf = *(const short8*)((const char*)t_lds + tb);
        short8 hf = {0, 0, 0, 0, 0, 0, 0, 0};
        if (arv && k0 < DIM) {
            const float* hp = h0 + (size_t)arow * DIM + k0;
            hf = pack_bf8(*(const float4*)hp, *(const float4*)(hp + 4));
        }
        const unsigned short* wp1 = wihb + (size_t)(ntlo * 32 + rl) * KPAD + k0;
        const unsigned short* wp2 = whhb + (size_t)(ntlo * 32 + rl) * KPAD + k0;
        #pragma unroll
        for (int t = 0; t < 4; ++t) {
            if (ntlo + t < 7) {
                short8 bf1 = *(const short8*)(wp1 + t * 32 * KPAD);
                o[t] = __builtin_amdgcn_mfma_f32_32x32x16_bf16(tf, bf1, o[t], 0, 0, 0);
                short8 bf2 = *(const short8*)(wp2 + t * 32 * KPAD);
                o[t] = __builtin_amdgcn_mfma_f32_32x32x16_bf16(hf, bf2, o[t], 0, 0, 0);
            }
        }
    }
    #pragma unroll
    for (int t = 0; t < 4; ++t) {
        if (ntlo + t >= 7) continue;
        int gc = (ntlo + t) * 32 + rl;
        if (gc >= DIM) continue;
        float bias = b_ih[gc] + b_hh[gc];
        #pragma unroll
        for (int r = 0; r < 16; ++r) {
            int gr = row0 + (r & 3) + 8 * (r >> 2) + 4 * hl;
            if (gr < N_NODES)
                out[(size_t)gr * DIM + gc] = tanhf(o[t][r] + bias);
        }
    }
}

// ---------------------------------------------------------------- launch
extern "C" void kernel_launch(void* const* d_in, const int* in_sizes, int n_in,
                              void* d_out, int out_size, void* d_ws, size_t ws_size,
                              hipStream_t stream) {
    const float* node_feat = (const float*)d_in[0];
    const float* dyn_emb   = (const float*)d_in[1];
    const int*   src       = (const int*)  d_in[2];
    const int*   dst       = (const int*)  d_in[3];
    const int*   etypes    = (const int*)  d_in[4];
    const float* w1        = (const float*)d_in[5];
    const float* loop_w1   = (const float*)d_in[6];
    const float* b1        = (const float*)d_in[7];
    const float* w2        = (const float*)d_in[8];
    const float* loop_w2   = (const float*)d_in[9];
    const float* b2        = (const float*)d_in[10];
    const float* W_ih      = (const float*)d_in[11];
    const float* W_hh      = (const float*)d_in[12];
    const float* b_ih      = (const float*)d_in[13];
    const float* b_hh      = (const float*)d_in[14];
    float* out = (float*)d_out;

    // workspace layout
    int*   degi = (int*)d_ws;                          // 51200
    int*   pos  = degi + 51200;                        // 51200
    int*   bsum = pos  + 51200;                        // 256
    int2*  se   = (int2*)(bsum + 256);                 // 800000 int2 (6.4 MB)
    float* agg  = (float*)(se + N_EDGES);              // N*D fp32 (40 MB)
    unsigned short* hb  = (unsigned short*)(agg + (size_t)N_NODES * DIM);  // 50048*224
    unsigned short* w1T = hb  + (size_t)NROWPAD * KPAD;
    unsigned short* w2T = w1T + KPAD * KPAD;
    unsigned short* wihb = w2T + KPAD * KPAD;
    unsigned short* whhb = wihb + KPAD * KPAD;

    hipMemsetAsync(degi, 0, 51200 * sizeof(int), stream);

    // CSR build
    deg_int_kernel<<<(N_EDGES + 255) / 256, 256, 0, stream>>>(dst, degi);
    scanA<<<NB_SCAN, 256, 0, stream>>>(degi, pos, bsum);
    scanB<<<1, 256, 0, stream>>>(bsum);
    scanC<<<NB_SCAN, 256, 0, stream>>>(pos, bsum);
    fill_kernel<<<(N_EDGES + 255) / 256, 256, 0, stream>>>(src, dst, etypes, pos, se);

    // weight prep (bf16)
    prep_wT<<<(KPAD * KPAD + 255) / 256, 256, 0, stream>>>(loop_w1, w1T);
    prep_wT<<<(KPAD * KPAD + 255) / 256, 256, 0, stream>>>(loop_w2, w2T);
    prep_w <<<(KPAD * KPAD + 255) / 256, 256, 0, stream>>>(W_ih, wihb);
    prep_w <<<(KPAD * KPAD + 255) / 256, 256, 0, stream>>>(W_hh, whhb);

    // ---- layer 1
    gatherP_f32<<<(N_NODES * 64 + 255) / 256, 256, 0, stream>>>(
        node_feat, se, pos, degi, w1, agg);
    gemm1_kernel<<<(N_NODES + 31) / 32, 128, 0, stream>>>(
        node_feat, agg, b1, w1T, hb);

    // ---- layer 2
    gatherP_bf16<<<(N_NODES * 64 + 255) / 256, 256, 0, stream>>>(
        hb, se, pos, degi, w2, agg);

    // ---- fused layer-2 dense + RNN cell
    gemm2_kernel<<<(N_NODES + 31) / 32, 128, 0, stream>>>(
        hb, agg, b2, w2T, dyn_emb, wihb, whhb, b_ih, b_hh, out);
}